// Round 6
// baseline (1673.103 us; speedup 1.0000x reference)
//
#include <hip/hip_runtime.h>

// LiquidNN LTC: B=512, S=512, D=H=128, O=1, UNFOLDS=6, dt=0.1, tau=1.
// R6: fix the AGPR-demotion confound. Serial phase now uses 2 waves/block,
// ONE output per lane (od = tid, full K) -> weight demand 64 v2h = 64 VGPRs
// (R5's 128-reg demand forced AGPR demotion; v_dot2 can't source AGPRs ->
// ~128 chained v_accvgpr_read per round = the measured 1128-cyc rounds).
// Inter-wave h exchange: double-buffered hbuf + ONE __syncthreads per unfold.
// Phase 1 (unchanged): xin GEMM into d_ws as packed f16 pairs (67 MB).
// Fallback if ws too small: R1-style fused kernel.

typedef _Float16 v2h __attribute__((ext_vector_type(2)));

#define S_LEN 512
#define HDIM 128
#define BATCH 512
#define NUNF 6
#define DTC 0.1f

__device__ __forceinline__ v2h pk2h(float a, float b) {
    return __builtin_bit_cast(v2h, __builtin_amdgcn_cvt_pkrtz(a, b));
}

__device__ __forceinline__ float fast_tanh(float y) {
    // tanh(y) = 1 - 2/(e^{2y}+1); exp+rcp based, NaN-free at +-inf
    float u = __expf(2.0f * y);
    return 1.0f - __fdividef(2.0f, u + 1.0f);
}

// ---------------- Phase 1: input-map GEMM (unchanged from R5) ----------------
__global__ __launch_bounds__(256, 2)
void xin_kernel(const float* __restrict__ x,
                const float* __restrict__ W_in,
                const float* __restrict__ b_in,
                unsigned int* __restrict__ xin)
{
    __shared__ __align__(16) _Float16 xt[128 * HDIM];   // 32 KB
    const int tid  = threadIdx.x;
    const int w    = tid >> 6;
    const int lane = tid & 63;
    const int bs0  = blockIdx.x * 128;

    const float4* xg = reinterpret_cast<const float4*>(x + (size_t)bs0 * HDIM);
#pragma unroll
    for (int i = 0; i < 16; ++i) {
        int idx = i * 1024 + tid * 4;
        float4 v = xg[idx >> 2];
        v2h* d = reinterpret_cast<v2h*>(xt + idx);
        d[0] = pk2h(v.x, v.y);
        d[1] = pk2h(v.z, v.w);
    }

    v2h wi0[64], wi1[64];
    {
        const float4* r0 = reinterpret_cast<const float4*>(W_in + (size_t)lane * HDIM);
        const float4* r1 = reinterpret_cast<const float4*>(W_in + (size_t)(lane + 64) * HDIM);
#pragma unroll
        for (int j = 0; j < 32; ++j) {
            float4 f = r0[j];
            wi0[2*j]   = pk2h(f.x, f.y);
            wi0[2*j+1] = pk2h(f.z, f.w);
            float4 g = r1[j];
            wi1[2*j]   = pk2h(g.x, g.y);
            wi1[2*j+1] = pk2h(g.z, g.w);
        }
    }
    const float bi0 = b_in[lane], bi1 = b_in[lane + 64];
    __syncthreads();

    for (int rr = 0; rr < 32; ++rr) {
        const int r = w * 32 + rr;
        const float4* hp = reinterpret_cast<const float4*>(xt + r * HDIM);
        float a0 = 0.f, a1 = 0.f, c0 = 0.f, c1 = 0.f;
#pragma unroll
        for (int j = 0; j < 16; ++j) {
            float4 q = hp[j];
            const v2h* hh = reinterpret_cast<const v2h*>(&q);
            a0 = __builtin_amdgcn_fdot2(wi0[4*j+0], hh[0], a0, false);
            a1 = __builtin_amdgcn_fdot2(wi0[4*j+1], hh[1], a1, false);
            a0 = __builtin_amdgcn_fdot2(wi0[4*j+2], hh[2], a0, false);
            a1 = __builtin_amdgcn_fdot2(wi0[4*j+3], hh[3], a1, false);
            c0 = __builtin_amdgcn_fdot2(wi1[4*j+0], hh[0], c0, false);
            c1 = __builtin_amdgcn_fdot2(wi1[4*j+1], hh[1], c1, false);
            c0 = __builtin_amdgcn_fdot2(wi1[4*j+2], hh[2], c0, false);
            c1 = __builtin_amdgcn_fdot2(wi1[4*j+3], hh[3], c1, false);
        }
        v2h pk = pk2h(a0 + a1 + bi0, c0 + c1 + bi1);
        xin[(size_t)(bs0 + r) * 64 + lane] = __builtin_bit_cast(unsigned int, pk);
    }
}

// ---------------- Phase 2: serial recurrence, 2 waves, 1 output/lane --------
__global__ __launch_bounds__(128, 1)
void ltc_kernel(const unsigned int* __restrict__ xin,
                const float* __restrict__ W_r,
                const float* __restrict__ b_r,
                const float* __restrict__ W_fc,
                const float* __restrict__ b_fc,
                float* __restrict__ out)
{
    const int b   = blockIdx.x;
    const int tid = threadIdx.x;      // 0..127
    const int w   = tid >> 6;         // wave id
    const int ln  = tid & 63;
    const int od  = tid;              // owned output (full K)

    __shared__ __align__(16) _Float16 hbuf[2][HDIM];  // double buffer
    __shared__ float red[2];

    // W_r row od, natural consecutive f16 pairing: 64 v2h = 64 VGPRs
    v2h wr[64];
    {
        const float4* wp = reinterpret_cast<const float4*>(W_r + (size_t)od * HDIM);
#pragma unroll
        for (int j = 0; j < 32; ++j) {
            float4 f = wp[j];
            wr[2*j]   = pk2h(f.x, f.y);
            wr[2*j+1] = pk2h(f.z, f.w);
        }
    }
    const float brv = b_r[od];
    const unsigned int* xrow = xin + (size_t)b * S_LEN * 64;

    float h = 0.f;
    hbuf[0][tid] = (_Float16)0.f;
    __syncthreads();

    unsigned int xcur = xrow[ln];     // pair (xin[ln], xin[ln+64]); wave picks half
    for (int s = 0; s < S_LEN; ++s) {
        unsigned int xnext = 0;
        if (s + 1 < S_LEN) xnext = xrow[(s + 1) * 64 + ln];   // prefetch
        v2h xp = __builtin_bit_cast(v2h, xcur);
        const float xs = (w ? (float)xp.y : (float)xp.x) + brv;  // xin has b_in

#pragma unroll
        for (int u = 0; u < NUNF; ++u) {
            const float4* hp = reinterpret_cast<const float4*>(hbuf[u & 1]);
            float a0 = 0.f, a1 = 0.f, a2 = 0.f, a3 = 0.f;
#pragma unroll
            for (int j = 0; j < 16; ++j) {
                float4 q = hp[j];                 // broadcast ds_read_b128
                const v2h* hh = reinterpret_cast<const v2h*>(&q);
                a0 = __builtin_amdgcn_fdot2(wr[4*j+0], hh[0], a0, false);
                a1 = __builtin_amdgcn_fdot2(wr[4*j+1], hh[1], a1, false);
                a2 = __builtin_amdgcn_fdot2(wr[4*j+2], hh[2], a2, false);
                a3 = __builtin_amdgcn_fdot2(wr[4*j+3], hh[3], a3, false);
            }
            float v = fast_tanh(xs + (a0 + a1) + (a2 + a3));
            h = h + DTC * (v - h);                // tau=1: h += dt*(-h+v)
            hbuf[(u + 1) & 1][od] = (_Float16)h;  // 128 distinct b16 slots (2-way, free)
            __syncthreads();                      // ONE barrier per unfold
        }
        xcur = xnext;
    }

    // epilogue: out[b] = h . W_fc + b_fc (cross-wave via LDS)
    float partial = h * W_fc[od];
#pragma unroll
    for (int d = 1; d < 64; d <<= 1) partial += __shfl_xor(partial, d);
    if (ln == 0) red[w] = partial;
    __syncthreads();
    if (tid == 0) out[b] = red[0] + red[1] + b_fc[0];
}

// ---------------- Fallback (fused single kernel) ----------------
__global__ __launch_bounds__(256, 2)
void ltc_fallback(const float* __restrict__ x,
                  const float* __restrict__ W_in,
                  const float* __restrict__ b_in,
                  const float* __restrict__ W_r,
                  const float* __restrict__ b_r,
                  const float* __restrict__ W_fc,
                  const float* __restrict__ b_fc,
                  float* __restrict__ out)
{
    const int b     = blockIdx.x;
    const int tid   = threadIdx.x;
    const int o     = tid >> 1;
    const int kh    = tid & 1;
    const int kbase = kh * 64;

    __shared__ __align__(16) _Float16 hbuf[2][HDIM];
    __shared__ __align__(16) _Float16 xbuf[2][HDIM];
    __shared__ float red[4];

    v2h wr[32], wi[32];
    {
        const float4* wrp = reinterpret_cast<const float4*>(W_r  + o * HDIM + kbase);
        const float4* wip = reinterpret_cast<const float4*>(W_in + o * HDIM + kbase);
#pragma unroll
        for (int j = 0; j < 16; ++j) {
            float4 f = wrp[j];
            wr[2*j]   = pk2h(f.x, f.y);
            wr[2*j+1] = pk2h(f.z, f.w);
            float4 g = wip[j];
            wi[2*j]   = pk2h(g.x, g.y);
            wi[2*j+1] = pk2h(g.z, g.w);
        }
    }
    const float binv = b_in[o];
    const float brv  = b_r[o];
    const float* x_row = x + (size_t)b * S_LEN * HDIM;
    float h_o = 0.0f;

    if (tid < HDIM) {
        xbuf[0][tid] = (_Float16)x_row[tid];
        hbuf[0][tid] = (_Float16)0.0f;
    }
    __syncthreads();

    for (int s = 0; s < S_LEN; ++s) {
        float xnext = 0.0f;
        if (tid < HDIM && s + 1 < S_LEN)
            xnext = x_row[(size_t)(s + 1) * HDIM + tid];

        float xin_o;
        {
            const float4* hp = reinterpret_cast<const float4*>(&xbuf[s & 1][kbase]);
            float4 hv[8];
#pragma unroll
            for (int j = 0; j < 8; ++j) hv[j] = hp[j];
            const v2h* hh = reinterpret_cast<const v2h*>(hv);
            float a0 = 0.f, a1 = 0.f, a2 = 0.f, a3 = 0.f;
#pragma unroll
            for (int j = 0; j < 32; j += 4) {
                a0 = __builtin_amdgcn_fdot2(wi[j],   hh[j],   a0, false);
                a1 = __builtin_amdgcn_fdot2(wi[j+1], hh[j+1], a1, false);
                a2 = __builtin_amdgcn_fdot2(wi[j+2], hh[j+2], a2, false);
                a3 = __builtin_amdgcn_fdot2(wi[j+3], hh[j+3], a3, false);
            }
            float sum = (a0 + a1) + (a2 + a3);
            sum += __shfl_xor(sum, 1);
            xin_o = sum + binv;
        }

#pragma unroll
        for (int u = 0; u < NUNF; ++u) {
            const float4* hp = reinterpret_cast<const float4*>(&hbuf[u & 1][kbase]);
            float4 hv[8];
#pragma unroll
            for (int j = 0; j < 8; ++j) hv[j] = hp[j];
            const v2h* hh = reinterpret_cast<const v2h*>(hv);
            float a0 = 0.f, a1 = 0.f, a2 = 0.f, a3 = 0.f;
#pragma unroll
            for (int j = 0; j < 32; j += 4) {
                a0 = __builtin_amdgcn_fdot2(wr[j],   hh[j],   a0, false);
                a1 = __builtin_amdgcn_fdot2(wr[j+1], hh[j+1], a1, false);
                a2 = __builtin_amdgcn_fdot2(wr[j+2], hh[j+2], a2, false);
                a3 = __builtin_amdgcn_fdot2(wr[j+3], hh[j+3], a3, false);
            }
            float sum = (a0 + a1) + (a2 + a3);
            sum += __shfl_xor(sum, 1);
            float yv = xin_o + brv + sum;
            float v  = fast_tanh(yv);
            h_o = h_o + DTC * (v - h_o);
            if ((tid & 1) == 0)
                hbuf[(u + 1) & 1][o] = (_Float16)h_o;
            if (u == NUNF - 1 && tid < HDIM && s + 1 < S_LEN)
                xbuf[(s + 1) & 1][tid] = (_Float16)xnext;
            __syncthreads();
        }
    }

    float partial = 0.0f;
    if ((tid & 1) == 0) partial = h_o * W_fc[o];
#pragma unroll
    for (int d = 1; d < 64; d <<= 1) partial += __shfl_xor(partial, d);
    if ((tid & 63) == 0) red[tid >> 6] = partial;
    __syncthreads();
    if (tid == 0) out[b] = red[0] + red[1] + red[2] + red[3] + b_fc[0];
}

extern "C" void kernel_launch(void* const* d_in, const int* in_sizes, int n_in,
                              void* d_out, int out_size, void* d_ws, size_t ws_size,
                              hipStream_t stream) {
    const float* x    = (const float*)d_in[0];
    const float* W_in = (const float*)d_in[1];
    const float* b_in = (const float*)d_in[2];
    const float* W_r  = (const float*)d_in[3];
    const float* b_r  = (const float*)d_in[4];
    const float* W_fc = (const float*)d_in[5];
    const float* b_fc = (const float*)d_in[6];
    float* outp = (float*)d_out;
    (void)in_sizes; (void)n_in; (void)out_size;

    const size_t need = (size_t)BATCH * S_LEN * 64 * sizeof(unsigned int); // 67.1 MB
    if (ws_size >= need) {
        unsigned int* xin = (unsigned int*)d_ws;
        xin_kernel<<<dim3(2048), dim3(256), 0, stream>>>(x, W_in, b_in, xin);
        ltc_kernel<<<dim3(512), dim3(128), 0, stream>>>(xin, W_r, b_r, W_fc, b_fc, outp);
    } else {
        ltc_fallback<<<dim3(512), dim3(256), 0, stream>>>(x, W_in, b_in, W_r, b_r, W_fc, b_fc, outp);
    }
}